// Round 16
// baseline (20.225 us; speedup 1.0000x reference)
//
#include <hip/hip_runtime.h>
#include <math.h>

#define PI_F 3.14159265358979323846f

typedef int i32x2 __attribute__((ext_vector_type(2)));

// ===========================================================================
// Compile-time Pauli engine (verified R9-R15, absmax 0.0156).
// ===========================================================================
struct PS { int x, z, ph; };

constexpr int SLEN_[8]      = {3,3,2,2,3,3,4,4};
constexpr int SWIRES_[8][4] = {{2,4,6,0},{3,5,7,0},{0,2,0,0},{1,3,0,0},
                               {0,2,4,0},{1,3,5,0},{0,2,4,6},{1,3,5,7}};
constexpr int NCODE_[8]     = {27,27,9,9,27,27,81,81};
constexpr int NTERMS = 288;
constexpr int NCHUNK = 16;
constexpr int CLEN   = 18;

constexpr int cpopc(int v){ int c=0; while(v){ c += v&1; v >>= 1; } return c; }

constexpr PS pmul(PS a, PS b) {
  return PS{ a.x ^ b.x, a.z ^ b.z, (a.ph + b.ph + 2*cpopc(a.z & b.x)) & 3 };
}
constexpr PS pcnot(PS s, int c, int t) {
  PS r = s;
  if ((s.x >> c) & 1) r.x ^= (1 << t);
  if ((s.z >> t) & 1) r.z ^= (1 << c);
  return r;
}
constexpr PS buildTerm(int w, int code) {
  PS s{0,0,0};
  int cc = code;
  for (int i = 0; i < SLEN_[w]; ++i) {
    int v = SWIRES_[w][i];
    int k = cc % 3; cc /= 3;              // 0->X, 1->Y, 2->Z
    PS comp = (k==0) ? PS{1<<v, 0, 0} : (k==1) ? PS{1<<v, 1<<v, 1} : PS{0, 1<<v, 0};
    s = pmul(s, comp);
  }
  for (int i = 7; i >= 0; --i) s = pcnot(s, i, (i+1)&7);   // Ring1 conj
  return s;
}
constexpr int wOf(int t)   { int w=0, acc=0; while (t >= acc + NCODE_[w]) { acc += NCODE_[w]; ++w; } return w; }
constexpr int codeOf(int t){ int w=0, acc=0; while (t >= acc + NCODE_[w]) { acc += NCODE_[w]; ++w; } return t - acc; }
constexpr PS termOf(int t) { return buildTerm(wOf(t), codeOf(t)); }
constexpr float signOf(int t) {
  PS s = termOf(t);
  int e = (s.ph - cpopc(s.x & s.z)) & 3;  // <XZ> = -i<Y>: remove i per Y
  return (e == 0) ? 1.0f : -1.0f;
}

// ---- per-term factor descriptors: 2 bits/wire, 0=1, 1=bx, 2=by, 3=bz ------
struct DTab { unsigned int d[NTERMS]; };
constexpr DTab mkDesc() {
  DTab tb{};
  for (int t = 0; t < NTERMS; ++t) {
    PS s = termOf(t);
    unsigned int de = 0;
    for (int u = 0; u < 8; ++u) {
      const int xb = (s.x >> u) & 1, zb = (s.z >> u) & 1;
      const unsigned int b = (xb && zb) ? 2u : xb ? 1u : zb ? 3u : 0u;
      de |= b << (2*u);
    }
    tb.d[t] = de;
  }
  return tb;
}
static __constant__ DTab DESC_TAB = mkDesc();

// ---- per-chunk accumulator routing (<=1 group boundary per 18-term chunk) -
struct CTab { int wiA[NCHUNK]; int wiB[NCHUNK]; int split[NCHUNK]; };
constexpr CTab mkChunk() {
  CTab c{};
  for (int k = 0; k < NCHUNK; ++k) {
    const int t0 = k*CLEN;
    c.wiA[k] = wOf(t0);
    c.wiB[k] = wOf(t0 + CLEN - 1);
    int sp = t0 + CLEN;
    for (int t = t0; t < t0 + CLEN; ++t)
      if (wOf(t) != c.wiA[k]) { sp = t; break; }
    c.split[k] = sp;
  }
  return c;
}
static __constant__ CTab CHUNK_TAB = mkChunk();

// ===========================================================================
// Register-guaranteed 8-float struct (rule #20 scratch-proofing).
// ===========================================================================
struct B8 { float a0,a1,a2,a3,a4,a5,a6,a7; };
template<int U> static __device__ __forceinline__ float& r8(B8& b) {
  if constexpr (U==0) return b.a0; else if constexpr (U==1) return b.a1;
  else if constexpr (U==2) return b.a2; else if constexpr (U==3) return b.a3;
  else if constexpr (U==4) return b.a4; else if constexpr (U==5) return b.a5;
  else if constexpr (U==6) return b.a6; else return b.a7;
}
template<int U> static __device__ __forceinline__ float g8(const B8& b) {
  if constexpr (U==0) return b.a0; else if constexpr (U==1) return b.a1;
  else if constexpr (U==2) return b.a2; else if constexpr (U==3) return b.a3;
  else if constexpr (U==4) return b.a4; else if constexpr (U==5) return b.a5;
  else if constexpr (U==6) return b.a6; else return b.a7;
}

// wave-uniform 2-bit factor select (s_cselect masks + v_cndmask, no branch)
template<int U>
static __device__ __forceinline__ float fsel(unsigned int de,
    const B8& bx, const B8& by, const B8& bz)
{
  const unsigned int b = (de >> (2*U)) & 3u;
  return (b & 2u) ? ((b & 1u) ? g8<U>(bz) : g8<U>(by))
                  : ((b & 1u) ? g8<U>(bx) : 1.0f);
}

template<int W>
static __device__ __forceinline__ void loadBloch(
    const float* __restrict__ row, B8& bx, B8& by, B8& bz)
{
  r8<W>(bx) = row[W*3 + 0];
  r8<W>(by) = row[W*3 + 1];
  r8<W>(bz) = row[W*3 + 2];
}

// ===========================================================================
// Cross-lane primitives (verified R5-R15).
// ===========================================================================
template<int CTRL>
static __device__ __forceinline__ float dppf(float v) {
  return __builtin_bit_cast(float,
    __builtin_amdgcn_update_dpp(0, __builtin_bit_cast(int, v), CTRL, 0xF, 0xF, false));
}
static __device__ __forceinline__ float pswap32(float v, int lane) {
  i32x2 r = __builtin_amdgcn_permlane32_swap(
      __builtin_bit_cast(int, v), __builtin_bit_cast(int, v), false, false);
  return __builtin_bit_cast(float, (lane & 32) ? r.x : r.y);
}
static __device__ __forceinline__ float pswap16(float v, int lane) {
  i32x2 r = __builtin_amdgcn_permlane16_swap(
      __builtin_bit_cast(int, v), __builtin_bit_cast(int, v), false, false);
  return __builtin_bit_cast(float, (lane & 16) ? r.x : r.y);
}
template<int MASK>
static __device__ __forceinline__ float lxor(float v, int lane) {
  if constexpr (MASK == 1)       return dppf<0xB1>(v);
  else if constexpr (MASK == 2)  return dppf<0x4E>(v);
  else if constexpr (MASK == 4)  return dppf<0x1B>(dppf<0x141>(v));
  else if constexpr (MASK == 8)  return dppf<0x128>(v);
  else if constexpr (MASK == 16) return pswap16(v, lane);
  else if constexpr (MASK == 32) return pswap32(v, lane);
  else return __shfl_xor(v, MASK, 64);
}
template<int SRC>
static __device__ __forceinline__ float breadl(float v) {
  return __builtin_bit_cast(float,
    __builtin_amdgcn_readlane(__builtin_bit_cast(int, v), SRC));
}

// ===========================================================================
// SINGLE fused kernel, SMALL SHARED CODE PATH (I-cache fix, R15->R16).
// 1024-thread block (16 waves) per 64 elements.
//  Phase 0a: trig (8 thr) + zero part
//  Phase 0b: 288 coefficients (288 thr) + Bloch once (thr 512..1023)
//  Phase 1:  wave k: data-driven 18-term chunk, same code for all waves
//  Phase 2:  combine partials -> zvc[64][8]
//  Phase 3:  wave k projects+LNs elements [4k,4k+4)
// ===========================================================================
__global__ __launch_bounds__(1024) void qbranch_fused(
    const float* __restrict__ x,       // (B,8)
    const float* __restrict__ weights, // (2,8,3)
    const float* __restrict__ Wm,      // (8,64)
    const float* __restrict__ bias,    // (64)
    const float* __restrict__ gamma,   // (64)
    const float* __restrict__ beta,    // (64)
    float* __restrict__ out,           // (B,64)
    int B)
{
  __shared__ float u0s[8][4];
  __shared__ float gsh[8][3];
  __shared__ float cf[NTERMS];
  __shared__ float blo[64*25];        // [elem][wire*3+c], pad 25
  __shared__ float part[16][64][9];   // [chunk][lane][wi], pad 9
  __shared__ float zvc[64][8];

  const int tid  = threadIdx.x;
  const int k    = tid >> 6;          // wave id 0..15
  const int lane = tid & 63;
  const int base = blockIdx.x * 64;

  // --- Phase 0a: trig + zero part ----------------------------------------
  if (tid < 8) {
    float phi = weights[tid*3 + 0], th = weights[tid*3 + 1], om = weights[tid*3 + 2];
    float ct = cosf(th*0.5f), st = sinf(th*0.5f);
    float ap = (phi + om)*0.5f, am = (phi - om)*0.5f;
    u0s[tid][0] =  cosf(ap)*ct;   // u00r
    u0s[tid][1] = -sinf(ap)*ct;   // u00i
    u0s[tid][2] = -cosf(am)*st;   // u01r
    u0s[tid][3] = -sinf(am)*st;   // u01i
    float phi1 = weights[(8+tid)*3 + 0], th1 = weights[(8+tid)*3 + 1];
    float s1 = sinf(th1), c1 = cosf(th1);
    gsh[tid][0] = -s1*cosf(phi1);
    gsh[tid][1] =  s1*sinf(phi1);
    gsh[tid][2] =  c1;
  }
  {
    float* p = (float*)part;
#pragma unroll
    for (int i = 0; i < 9; ++i) p[tid + i*1024] = 0.f;
  }
  __syncthreads();

  // --- Phase 0b: coefficients + Bloch once --------------------------------
  if (tid < NTERMS) {
    int ww = wOf(tid), code = codeOf(tid);
    float c = signOf(tid);
    int cc = code;
    for (int i = 0; i < SLEN_[ww]; ++i) {
      int kk = cc % 3; cc /= 3;
      c *= gsh[SWIRES_[ww][i]][kk];
    }
    cf[tid] = c;
  }
  if (tid >= 512) {
    const int t   = tid - 512;
    const int e   = t >> 3;           // element 0..63
    const int w   = t & 7;            // wire
    const int el  = (base + e < B) ? (base + e) : (B - 1);
    const float xv = x[(size_t)el*8 + w];
    const float th = 1.f - 2.f / (__expf(2.f*xv) + 1.f);   // tanh
    const float ha = th * (PI_F * 0.5f);
    const float c = __cosf(ha), s = __sinf(ha);
    const float u00r = u0s[w][0], u00i = u0s[w][1];
    const float u01r = u0s[w][2], u01i = u0s[w][3];
    const float x0r =  u00r*c + u01i*s;
    const float x0i =  u00i*c - u01r*s;
    const float x1r = -u01r*c - u00i*s;
    const float x1i =  u01i*c - u00r*s;
    float* row = blo + e*25 + w*3;
    row[0] = 2.f*(x0r*x1r + x0i*x1i);
    row[1] = 2.f*(x0r*x1i - x0i*x1r);
    row[2] = x0r*x0r + x0i*x0i - x1r*x1r - x1i*x1i;
  }
  __syncthreads();

  // --- Phase 1: data-driven 18-term chunk (SAME code for every wave) ------
  B8 bx, by, bz;
  {
    const float* row = blo + lane*25;
    loadBloch<0>(row, bx, by, bz);
    loadBloch<1>(row, bx, by, bz);
    loadBloch<2>(row, bx, by, bz);
    loadBloch<3>(row, bx, by, bz);
    loadBloch<4>(row, bx, by, bz);
    loadBloch<5>(row, bx, by, bz);
    loadBloch<6>(row, bx, by, bz);
    loadBloch<7>(row, bx, by, bz);
  }

  const unsigned int* __restrict__ dp = DESC_TAB.d + k*CLEN;  // s_load (uniform)
  const float* __restrict__ cfp = cf + k*CLEN;                // LDS broadcast
  const int wiA = CHUNK_TAB.wiA[k];
  const int wiB = CHUNK_TAB.wiB[k];
  const int spl = CHUNK_TAB.split[k];

  float accA = 0.f, accB = 0.f;
#pragma unroll
  for (int i = 0; i < CLEN; ++i) {
    const unsigned int de = dp[i];
    float p = cfp[i];
    p *= fsel<0>(de, bx, by, bz);
    p *= fsel<1>(de, bx, by, bz);
    p *= fsel<2>(de, bx, by, bz);
    p *= fsel<3>(de, bx, by, bz);
    p *= fsel<4>(de, bx, by, bz);
    p *= fsel<5>(de, bx, by, bz);
    p *= fsel<6>(de, bx, by, bz);
    p *= fsel<7>(de, bx, by, bz);
    const bool inB = (k*CLEN + i) >= spl;   // wave-uniform
    accA += inB ? 0.f : p;
    accB += inB ? p : 0.f;
  }
  // wiB==wiA only when spl==end (accB==0); accA written last wins.
  part[k][lane][wiB] = accB;
  part[k][lane][wiA] = accA;
  __syncthreads();

  // --- Phase 2: combine -> zvc[elem][wi] (threads 0..511) -----------------
  if (tid < 512) {
    const int lr = tid >> 3;
    const int wi = tid & 7;
    float s = 0.f;
#pragma unroll
    for (int kk = 0; kk < 16; ++kk) s += part[kk][lr][wi];
    zvc[lr][wi] = s;
  }
  __syncthreads();

  // --- Phase 3: projection + LN. Wave k handles elements [4k, 4k+4) -------
  const int j = lane;
  const float w0 = Wm[0*64+j], w1 = Wm[1*64+j], w2 = Wm[2*64+j], w3 = Wm[3*64+j];
  const float w4 = Wm[4*64+j], w5 = Wm[5*64+j], w6 = Wm[6*64+j], w7 = Wm[7*64+j];
  const float bj = bias[j], gj = gamma[j], btj = beta[j];
  const bool lb0 = (lane & 1) != 0;

#pragma unroll
  for (int e = 0; e < 4; ++e) {
    const int l = k*4 + e;
    if (base + l >= B) break;
    const float s0 = zvc[l][0], s1 = zvc[l][1], s2 = zvc[l][2], s3 = zvc[l][3];
    const float s4 = zvc[l][4], s5 = zvc[l][5], s6 = zvc[l][6], s7 = zvc[l][7];
    float h = bj;
    h = fmaf(s0, w0, h); h = fmaf(s1, w1, h); h = fmaf(s2, w2, h); h = fmaf(s3, w3, h);
    h = fmaf(s4, w4, h); h = fmaf(s5, w5, h); h = fmaf(s6, w6, h); h = fmaf(s7, w7, h);

    float S = h, Q = h*h;
    float snd = lb0 ? S : Q;
    float acc = (lb0 ? Q : S) + lxor<1>(snd, lane);
    acc += lxor< 2>(acc, lane);
    acc += lxor< 4>(acc, lane);
    acc += lxor< 8>(acc, lane);
    acc += lxor<16>(acc, lane);
    acc += lxor<32>(acc, lane);
    const float Ssum = breadl<0>(acc);
    const float Qsum = breadl<1>(acc);
    const float mu  = Ssum * (1.f/64.f);
    const float var = fmaf(-mu, mu, Qsum * (1.f/64.f));

    out[(size_t)(base + l)*64 + j] =
        fmaf((h - mu) * rsqrtf(var + 1e-5f), gj, btj);
  }
}

// ---------------------------------------------------------------------------
extern "C" void kernel_launch(void* const* d_in, const int* in_sizes, int n_in,
                              void* d_out, int out_size, void* d_ws, size_t ws_size,
                              hipStream_t stream)
{
  const float* x       = (const float*)d_in[0];
  const float* weights = (const float*)d_in[1];
  const float* Wm      = (const float*)d_in[2];
  const float* bias    = (const float*)d_in[3];
  const float* gamma   = (const float*)d_in[4];
  const float* beta    = (const float*)d_in[5];
  float* out = (float*)d_out;

  const int B = in_sizes[0] / 8;

  hipLaunchKernelGGL(qbranch_fused, dim3((B + 63) / 64), dim3(1024), 0, stream,
                     x, weights, Wm, bias, gamma, beta, out, B);
}

// Round 17
// 11.195 us; speedup vs baseline: 1.8067x; 1.8067x over previous
//
#include <hip/hip_runtime.h>
#include <math.h>

#define PI_F 3.14159265358979323846f

typedef int i32x2 __attribute__((ext_vector_type(2)));

// ===========================================================================
// Compile-time Pauli engine (verified R9-R16, absmax 0.0156).
// Used ONLY at compile time now (constexpr tables); no runtime Pauli code.
// ===========================================================================
struct PS { int x, z, ph; };

constexpr int SLEN_[8]      = {3,3,2,2,3,3,4,4};
constexpr int SWIRES_[8][4] = {{2,4,6,0},{3,5,7,0},{0,2,0,0},{1,3,0,0},
                               {0,2,4,0},{1,3,5,0},{0,2,4,6},{1,3,5,7}};
constexpr int NCODE_[8]     = {27,27,9,9,27,27,81,81};
constexpr int NTERMS = 288;

constexpr int cpopc(int v){ int c=0; while(v){ c += v&1; v >>= 1; } return c; }

constexpr PS pmul(PS a, PS b) {
  return PS{ a.x ^ b.x, a.z ^ b.z, (a.ph + b.ph + 2*cpopc(a.z & b.x)) & 3 };
}
constexpr PS pcnot(PS s, int c, int t) {
  PS r = s;
  if ((s.x >> c) & 1) r.x ^= (1 << t);
  if ((s.z >> t) & 1) r.z ^= (1 << c);
  return r;
}
constexpr PS buildTerm(int w, int code) {
  PS s{0,0,0};
  int cc = code;
  for (int i = 0; i < SLEN_[w]; ++i) {
    int v = SWIRES_[w][i];
    int k = cc % 3; cc /= 3;              // 0->X, 1->Y, 2->Z
    PS comp = (k==0) ? PS{1<<v, 0, 0} : (k==1) ? PS{1<<v, 1<<v, 1} : PS{0, 1<<v, 0};
    s = pmul(s, comp);
  }
  for (int i = 7; i >= 0; --i) s = pcnot(s, i, (i+1)&7);   // Ring1 conj
  return s;
}
constexpr int wOf(int t)   { int w=0, acc=0; while (t >= acc + NCODE_[w]) { acc += NCODE_[w]; ++w; } return w; }
constexpr int codeOf(int t){ int w=0, acc=0; while (t >= acc + NCODE_[w]) { acc += NCODE_[w]; ++w; } return t - acc; }
constexpr PS termOf(int t) { return buildTerm(wOf(t), codeOf(t)); }
constexpr float signOf(int t) {
  PS s = termOf(t);
  int e = (s.ph - cpopc(s.x & s.z)) & 3;  // <XZ> = -i<Y>: remove i per Y
  return (e == 0) ? 1.0f : -1.0f;
}

// ---- constexpr coefficient descriptors: 4 bytes = indices into gshf[25]
//      (gshf[w*3+k], gshf[24]=1.0 identity), bit31 = negative sign ----------
struct CFD { unsigned int d[NTERMS]; };
constexpr CFD mkCFD() {
  CFD tb{};
  for (int t = 0; t < NTERMS; ++t) {
    const int w = wOf(t);
    int cc = codeOf(t);
    unsigned int by[4] = {24u, 24u, 24u, 24u};
    for (int i = 0; i < SLEN_[w]; ++i) {
      int k = cc % 3; cc /= 3;
      by[i] = (unsigned int)(SWIRES_[w][i]*3 + k);
    }
    unsigned int de = by[0] | (by[1] << 8) | (by[2] << 16) | (by[3] << 24);
    if (signOf(t) < 0.f) de |= 0x80000000u;
    tb.d[t] = de;
  }
  return tb;
}
static __constant__ CFD CFD_TAB = mkCFD();

// ===========================================================================
// Register-guaranteed 8-float struct (rule #20 scratch-proofing).
// ===========================================================================
struct B8 { float a0,a1,a2,a3,a4,a5,a6,a7; };
template<int U> static __device__ __forceinline__ float& r8(B8& b) {
  if constexpr (U==0) return b.a0; else if constexpr (U==1) return b.a1;
  else if constexpr (U==2) return b.a2; else if constexpr (U==3) return b.a3;
  else if constexpr (U==4) return b.a4; else if constexpr (U==5) return b.a5;
  else if constexpr (U==6) return b.a6; else return b.a7;
}
template<int U> static __device__ __forceinline__ float g8(const B8& b) {
  if constexpr (U==0) return b.a0; else if constexpr (U==1) return b.a1;
  else if constexpr (U==2) return b.a2; else if constexpr (U==3) return b.a3;
  else if constexpr (U==4) return b.a4; else if constexpr (U==5) return b.a5;
  else if constexpr (U==6) return b.a6; else return b.a7;
}

template<int T, int U>
static __device__ __forceinline__ float tfac(const B8& bx, const B8& by, const B8& bz) {
  constexpr PS s = termOf(T);
  constexpr bool xb = (s.x >> U) & 1, zb = (s.z >> U) & 1;
  if constexpr (xb && zb) return g8<U>(by);
  else if constexpr (xb)  return g8<U>(bx);
  else if constexpr (zb)  return g8<U>(bz);
  else                    return 1.0f;
}
template<int T>
static __device__ __forceinline__ float teval(const B8& bx, const B8& by, const B8& bz) {
  return tfac<T,0>(bx,by,bz) * tfac<T,1>(bx,by,bz) * tfac<T,2>(bx,by,bz) * tfac<T,3>(bx,by,bz)
       * tfac<T,4>(bx,by,bz) * tfac<T,5>(bx,by,bz) * tfac<T,6>(bx,by,bz) * tfac<T,7>(bx,by,bz);
}
template<int T, int TEND>
static __device__ __forceinline__ void evalRange(const float* __restrict__ cf,
    const B8& bx, const B8& by, const B8& bz, B8& zv) {
  if constexpr (T < TEND) {
    r8<wOf(T)>(zv) = fmaf(cf[T], teval<T>(bx,by,bz), r8<wOf(T)>(zv));
    evalRange<T+1, TEND>(cf, bx, by, bz, zv);
  }
}

template<int W>
static __device__ __forceinline__ void loadBloch(
    const float* __restrict__ row, B8& bx, B8& by, B8& bz)
{
  r8<W>(bx) = row[W*3 + 0];
  r8<W>(by) = row[W*3 + 1];
  r8<W>(bz) = row[W*3 + 2];
}

template<int WI>
static __device__ __forceinline__ void storePart(
    float part[8][64][9], const B8& zv, int k, int lane)
{
  if constexpr (WI < 8) {
    part[k][lane][WI] = g8<WI>(zv);
    storePart<WI+1>(part, zv, k, lane);
  }
}

// ===========================================================================
// Cross-lane primitives (verified R5-R16).
// ===========================================================================
template<int CTRL>
static __device__ __forceinline__ float dppf(float v) {
  return __builtin_bit_cast(float,
    __builtin_amdgcn_update_dpp(0, __builtin_bit_cast(int, v), CTRL, 0xF, 0xF, false));
}
static __device__ __forceinline__ float pswap32(float v, int lane) {
  i32x2 r = __builtin_amdgcn_permlane32_swap(
      __builtin_bit_cast(int, v), __builtin_bit_cast(int, v), false, false);
  return __builtin_bit_cast(float, (lane & 32) ? r.x : r.y);
}
static __device__ __forceinline__ float pswap16(float v, int lane) {
  i32x2 r = __builtin_amdgcn_permlane16_swap(
      __builtin_bit_cast(int, v), __builtin_bit_cast(int, v), false, false);
  return __builtin_bit_cast(float, (lane & 16) ? r.x : r.y);
}
template<int MASK>
static __device__ __forceinline__ float lxor(float v, int lane) {
  if constexpr (MASK == 1)       return dppf<0xB1>(v);
  else if constexpr (MASK == 2)  return dppf<0x4E>(v);
  else if constexpr (MASK == 4)  return dppf<0x1B>(dppf<0x141>(v));
  else if constexpr (MASK == 8)  return dppf<0x128>(v);
  else if constexpr (MASK == 16) return pswap16(v, lane);
  else if constexpr (MASK == 32) return pswap32(v, lane);
  else return __shfl_xor(v, MASK, 64);
}
template<int SRC>
static __device__ __forceinline__ float breadl(float v) {
  return __builtin_bit_cast(float,
    __builtin_amdgcn_readlane(__builtin_bit_cast(int, v), SRC));
}

// ===========================================================================
// SINGLE fused kernel. 512-thread block (8 waves) per 64 elements.
// 256 blocks -> TWO independent blocks per CU (barrier/serial overlap).
//  Phase 0a: trig (8 thr) -> LDS (gshf with identity slot [24])
//  Phase 0b: 288 coefs via constexpr descriptors (~15 instr each)
//            + Bloch once: thread t -> (elem=t>>3, wire=t&7)
//  Phase 1:  wave k evaluates template chunk [36k,36k+36) (lane = elem)
//  Phase 2:  combine partials -> zvc[64][8]
//  Phase 3:  wave k projects+LNs elements [8k,8k+8)
// ===========================================================================
__global__ __launch_bounds__(512) void qbranch_fused(
    const float* __restrict__ x,       // (B,8)
    const float* __restrict__ weights, // (2,8,3)
    const float* __restrict__ Wm,      // (8,64)
    const float* __restrict__ bias,    // (64)
    const float* __restrict__ gamma,   // (64)
    const float* __restrict__ beta,    // (64)
    float* __restrict__ out,           // (B,64)
    int B)
{
  __shared__ float u0s[8][4];
  __shared__ float gshf[25];          // [w*3+k]; [24] = 1.0 identity
  __shared__ float cf[NTERMS];
  __shared__ float blo[64*25];        // [elem][wire*3+c], pad 25 (6.4 KB)
  __shared__ float part[8][64][9];    // [chunk][lane][wi], pad 9 (18.4 KB)
  __shared__ float zvc[64][8];

  const int tid  = threadIdx.x;
  const int k    = tid >> 6;          // wave id 0..7
  const int lane = tid & 63;
  const int base = blockIdx.x * 64;

  // --- Phase 0a: trig ------------------------------------------------------
  if (tid < 8) {
    float phi = weights[tid*3 + 0], th = weights[tid*3 + 1], om = weights[tid*3 + 2];
    float ct = cosf(th*0.5f), st = sinf(th*0.5f);
    float ap = (phi + om)*0.5f, am = (phi - om)*0.5f;
    u0s[tid][0] =  cosf(ap)*ct;   // u00r
    u0s[tid][1] = -sinf(ap)*ct;   // u00i
    u0s[tid][2] = -cosf(am)*st;   // u01r
    u0s[tid][3] = -sinf(am)*st;   // u01i
    float phi1 = weights[(8+tid)*3 + 0], th1 = weights[(8+tid)*3 + 1];
    float s1 = sinf(th1), c1 = cosf(th1);
    gshf[tid*3 + 0] = -s1*cosf(phi1);
    gshf[tid*3 + 1] =  s1*sinf(phi1);
    gshf[tid*3 + 2] =  c1;
  }
  if (tid == 8) gshf[24] = 1.0f;
  __syncthreads();

  // --- Phase 0b: coefficients (constexpr descriptors) + Bloch once --------
  if (tid < NTERMS) {
    const unsigned int de = CFD_TAB.d[tid];
    float c = gshf[de & 0xFFu]
            * gshf[(de >> 8)  & 0xFFu]
            * gshf[(de >> 16) & 0xFFu]
            * gshf[(de >> 24) & 0x7Fu];
    cf[tid] = (de & 0x80000000u) ? -c : c;
  }
  {
    const int e   = tid >> 3;         // element 0..63
    const int w   = tid & 7;          // wire
    const int el  = (base + e < B) ? (base + e) : (B - 1);
    const float xv = x[(size_t)el*8 + w];
    const float th = 1.f - 2.f / (__expf(2.f*xv) + 1.f);   // tanh
    const float ha = th * (PI_F * 0.5f);
    const float c = __cosf(ha), s = __sinf(ha);
    const float u00r = u0s[w][0], u00i = u0s[w][1];
    const float u01r = u0s[w][2], u01i = u0s[w][3];
    const float x0r =  u00r*c + u01i*s;
    const float x0i =  u00i*c - u01r*s;
    const float x1r = -u01r*c - u00i*s;
    const float x1i =  u01i*c - u00r*s;
    float* row = blo + e*25 + w*3;
    row[0] = 2.f*(x0r*x1r + x0i*x1i);
    row[1] = 2.f*(x0r*x1i - x0i*x1r);
    row[2] = x0r*x0r + x0i*x0i - x1r*x1r - x1i*x1i;
  }
  __syncthreads();

  // --- Phase 1: load Bloch from LDS + this wave's 36-term chunk -----------
  B8 bx, by, bz;
  {
    const float* row = blo + lane*25;
    loadBloch<0>(row, bx, by, bz);
    loadBloch<1>(row, bx, by, bz);
    loadBloch<2>(row, bx, by, bz);
    loadBloch<3>(row, bx, by, bz);
    loadBloch<4>(row, bx, by, bz);
    loadBloch<5>(row, bx, by, bz);
    loadBloch<6>(row, bx, by, bz);
    loadBloch<7>(row, bx, by, bz);
  }

  B8 zv = {0.f,0.f,0.f,0.f,0.f,0.f,0.f,0.f};
  switch (k) {
    case 0: evalRange<  0,  36>(cf, bx, by, bz, zv); break;
    case 1: evalRange< 36,  72>(cf, bx, by, bz, zv); break;
    case 2: evalRange< 72, 108>(cf, bx, by, bz, zv); break;
    case 3: evalRange<108, 144>(cf, bx, by, bz, zv); break;
    case 4: evalRange<144, 180>(cf, bx, by, bz, zv); break;
    case 5: evalRange<180, 216>(cf, bx, by, bz, zv); break;
    case 6: evalRange<216, 252>(cf, bx, by, bz, zv); break;
    case 7: evalRange<252, 288>(cf, bx, by, bz, zv); break;
  }
  storePart<0>(part, zv, k, lane);
  __syncthreads();

  // --- Phase 2: combine -> zvc[elem][wi] ----------------------------------
  {
    const int lr = tid >> 3;
    const int wi = tid & 7;
    float s = 0.f;
#pragma unroll
    for (int kk = 0; kk < 8; ++kk) s += part[kk][lr][wi];
    zvc[lr][wi] = s;
  }
  __syncthreads();

  // --- Phase 3: projection + LN. Wave k handles elements [8k, 8k+8) -------
  const int j = lane;
  const float w0 = Wm[0*64+j], w1 = Wm[1*64+j], w2 = Wm[2*64+j], w3 = Wm[3*64+j];
  const float w4 = Wm[4*64+j], w5 = Wm[5*64+j], w6 = Wm[6*64+j], w7 = Wm[7*64+j];
  const float bj = bias[j], gj = gamma[j], btj = beta[j];
  const bool lb0 = (lane & 1) != 0;

#pragma unroll
  for (int e = 0; e < 8; ++e) {
    const int l = k*8 + e;
    if (base + l >= B) break;
    const float s0 = zvc[l][0], s1 = zvc[l][1], s2 = zvc[l][2], s3 = zvc[l][3];
    const float s4 = zvc[l][4], s5 = zvc[l][5], s6 = zvc[l][6], s7 = zvc[l][7];
    float h = bj;
    h = fmaf(s0, w0, h); h = fmaf(s1, w1, h); h = fmaf(s2, w2, h); h = fmaf(s3, w3, h);
    h = fmaf(s4, w4, h); h = fmaf(s5, w5, h); h = fmaf(s6, w6, h); h = fmaf(s7, w7, h);

    float S = h, Q = h*h;
    float snd = lb0 ? S : Q;
    float acc = (lb0 ? Q : S) + lxor<1>(snd, lane);
    acc += lxor< 2>(acc, lane);
    acc += lxor< 4>(acc, lane);
    acc += lxor< 8>(acc, lane);
    acc += lxor<16>(acc, lane);
    acc += lxor<32>(acc, lane);
    const float Ssum = breadl<0>(acc);
    const float Qsum = breadl<1>(acc);
    const float mu  = Ssum * (1.f/64.f);
    const float var = fmaf(-mu, mu, Qsum * (1.f/64.f));

    out[(size_t)(base + l)*64 + j] =
        fmaf((h - mu) * rsqrtf(var + 1e-5f), gj, btj);
  }
}

// ---------------------------------------------------------------------------
extern "C" void kernel_launch(void* const* d_in, const int* in_sizes, int n_in,
                              void* d_out, int out_size, void* d_ws, size_t ws_size,
                              hipStream_t stream)
{
  const float* x       = (const float*)d_in[0];
  const float* weights = (const float*)d_in[1];
  const float* Wm      = (const float*)d_in[2];
  const float* bias    = (const float*)d_in[3];
  const float* gamma   = (const float*)d_in[4];
  const float* beta    = (const float*)d_in[5];
  float* out = (float*)d_out;

  const int B = in_sizes[0] / 8;

  hipLaunchKernelGGL(qbranch_fused, dim3((B + 63) / 64), dim3(512), 0, stream,
                     x, weights, Wm, bias, gamma, beta, out, B);
}

// Round 18
// 11.090 us; speedup vs baseline: 1.8238x; 1.0094x over previous
//
#include <hip/hip_runtime.h>
#include <math.h>

#define PI_F 3.14159265358979323846f

typedef int i32x2 __attribute__((ext_vector_type(2)));

// ===========================================================================
// Compile-time Pauli engine (verified R9-R17, absmax 0.0156).
// Compile-time only; no runtime Pauli code in the kernel.
// ===========================================================================
struct PS { int x, z, ph; };

constexpr int SLEN_[8]      = {3,3,2,2,3,3,4,4};
constexpr int SWIRES_[8][4] = {{2,4,6,0},{3,5,7,0},{0,2,0,0},{1,3,0,0},
                               {0,2,4,0},{1,3,5,0},{0,2,4,6},{1,3,5,7}};
constexpr int NCODE_[8]     = {27,27,9,9,27,27,81,81};
constexpr int NTERMS = 288;

constexpr int cpopc(int v){ int c=0; while(v){ c += v&1; v >>= 1; } return c; }

constexpr PS pmul(PS a, PS b) {
  return PS{ a.x ^ b.x, a.z ^ b.z, (a.ph + b.ph + 2*cpopc(a.z & b.x)) & 3 };
}
constexpr PS pcnot(PS s, int c, int t) {
  PS r = s;
  if ((s.x >> c) & 1) r.x ^= (1 << t);
  if ((s.z >> t) & 1) r.z ^= (1 << c);
  return r;
}
constexpr PS buildTerm(int w, int code) {
  PS s{0,0,0};
  int cc = code;
  for (int i = 0; i < SLEN_[w]; ++i) {
    int v = SWIRES_[w][i];
    int k = cc % 3; cc /= 3;              // 0->X, 1->Y, 2->Z
    PS comp = (k==0) ? PS{1<<v, 0, 0} : (k==1) ? PS{1<<v, 1<<v, 1} : PS{0, 1<<v, 0};
    s = pmul(s, comp);
  }
  for (int i = 7; i >= 0; --i) s = pcnot(s, i, (i+1)&7);   // Ring1 conj
  return s;
}
constexpr int wOf(int t)   { int w=0, acc=0; while (t >= acc + NCODE_[w]) { acc += NCODE_[w]; ++w; } return w; }
constexpr int codeOf(int t){ int w=0, acc=0; while (t >= acc + NCODE_[w]) { acc += NCODE_[w]; ++w; } return t - acc; }
constexpr PS termOf(int t) { return buildTerm(wOf(t), codeOf(t)); }
constexpr float signOf(int t) {
  PS s = termOf(t);
  int e = (s.ph - cpopc(s.x & s.z)) & 3;  // <XZ> = -i<Y>: remove i per Y
  return (e == 0) ? 1.0f : -1.0f;
}

// ---- constexpr coefficient descriptors: 4 bytes = indices into gshf[25]
//      (gshf[w*3+k], gshf[24]=1.0 identity), bit31 = negative sign ----------
struct CFD { unsigned int d[NTERMS]; };
constexpr CFD mkCFD() {
  CFD tb{};
  for (int t = 0; t < NTERMS; ++t) {
    const int w = wOf(t);
    int cc = codeOf(t);
    unsigned int by[4] = {24u, 24u, 24u, 24u};
    for (int i = 0; i < SLEN_[w]; ++i) {
      int k = cc % 3; cc /= 3;
      by[i] = (unsigned int)(SWIRES_[w][i]*3 + k);
    }
    unsigned int de = by[0] | (by[1] << 8) | (by[2] << 16) | (by[3] << 24);
    if (signOf(t) < 0.f) de |= 0x80000000u;
    tb.d[t] = de;
  }
  return tb;
}
static __constant__ CFD CFD_TAB = mkCFD();

// ===========================================================================
// Register-guaranteed 8-float struct (rule #20 scratch-proofing).
// ===========================================================================
struct B8 { float a0,a1,a2,a3,a4,a5,a6,a7; };
template<int U> static __device__ __forceinline__ float& r8(B8& b) {
  if constexpr (U==0) return b.a0; else if constexpr (U==1) return b.a1;
  else if constexpr (U==2) return b.a2; else if constexpr (U==3) return b.a3;
  else if constexpr (U==4) return b.a4; else if constexpr (U==5) return b.a5;
  else if constexpr (U==6) return b.a6; else return b.a7;
}
template<int U> static __device__ __forceinline__ float g8(const B8& b) {
  if constexpr (U==0) return b.a0; else if constexpr (U==1) return b.a1;
  else if constexpr (U==2) return b.a2; else if constexpr (U==3) return b.a3;
  else if constexpr (U==4) return b.a4; else if constexpr (U==5) return b.a5;
  else if constexpr (U==6) return b.a6; else return b.a7;
}

template<int T, int U>
static __device__ __forceinline__ float tfac(const B8& bx, const B8& by, const B8& bz) {
  constexpr PS s = termOf(T);
  constexpr bool xb = (s.x >> U) & 1, zb = (s.z >> U) & 1;
  if constexpr (xb && zb) return g8<U>(by);
  else if constexpr (xb)  return g8<U>(bx);
  else if constexpr (zb)  return g8<U>(bz);
  else                    return 1.0f;
}
template<int T>
static __device__ __forceinline__ float teval(const B8& bx, const B8& by, const B8& bz) {
  return tfac<T,0>(bx,by,bz) * tfac<T,1>(bx,by,bz) * tfac<T,2>(bx,by,bz) * tfac<T,3>(bx,by,bz)
       * tfac<T,4>(bx,by,bz) * tfac<T,5>(bx,by,bz) * tfac<T,6>(bx,by,bz) * tfac<T,7>(bx,by,bz);
}
template<int T, int TEND>
static __device__ __forceinline__ void evalRange(const float* __restrict__ cf,
    const B8& bx, const B8& by, const B8& bz, B8& zv) {
  if constexpr (T < TEND) {
    r8<wOf(T)>(zv) = fmaf(cf[T], teval<T>(bx,by,bz), r8<wOf(T)>(zv));
    evalRange<T+1, TEND>(cf, bx, by, bz, zv);
  }
}

template<int W>
static __device__ __forceinline__ void loadBloch(
    const float* __restrict__ row, B8& bx, B8& by, B8& bz)
{
  r8<W>(bx) = row[W*3 + 0];
  r8<W>(by) = row[W*3 + 1];
  r8<W>(bz) = row[W*3 + 2];
}

template<int WI>
static __device__ __forceinline__ void storePart(
    float part[16][64][9], const B8& zv, int k, int lane)
{
  if constexpr (WI < 8) {
    part[k][lane][WI] = g8<WI>(zv);
    storePart<WI+1>(part, zv, k, lane);
  }
}

// ===========================================================================
// Cross-lane primitives (verified R5-R17).
// ===========================================================================
template<int CTRL>
static __device__ __forceinline__ float dppf(float v) {
  return __builtin_bit_cast(float,
    __builtin_amdgcn_update_dpp(0, __builtin_bit_cast(int, v), CTRL, 0xF, 0xF, false));
}
static __device__ __forceinline__ float pswap32(float v, int lane) {
  i32x2 r = __builtin_amdgcn_permlane32_swap(
      __builtin_bit_cast(int, v), __builtin_bit_cast(int, v), false, false);
  return __builtin_bit_cast(float, (lane & 32) ? r.x : r.y);
}
static __device__ __forceinline__ float pswap16(float v, int lane) {
  i32x2 r = __builtin_amdgcn_permlane16_swap(
      __builtin_bit_cast(int, v), __builtin_bit_cast(int, v), false, false);
  return __builtin_bit_cast(float, (lane & 16) ? r.x : r.y);
}
template<int MASK>
static __device__ __forceinline__ float lxor(float v, int lane) {
  if constexpr (MASK == 1)       return dppf<0xB1>(v);
  else if constexpr (MASK == 2)  return dppf<0x4E>(v);
  else if constexpr (MASK == 4)  return dppf<0x1B>(dppf<0x141>(v));
  else if constexpr (MASK == 8)  return dppf<0x128>(v);
  else if constexpr (MASK == 16) return pswap16(v, lane);
  else if constexpr (MASK == 32) return pswap32(v, lane);
  else return __shfl_xor(v, MASK, 64);
}
template<int SRC>
static __device__ __forceinline__ float breadl(float v) {
  return __builtin_bit_cast(float,
    __builtin_amdgcn_readlane(__builtin_bit_cast(int, v), SRC));
}

// ===========================================================================
// SINGLE fused kernel. 1024-thread block (16 waves) per 64 elements.
// 256 blocks = 1/CU, but 4 waves/SIMD during Phase 1 (vs R17's 2).
//  Phase 0a: trig (8 thr) -> u0s + gshf
//  Phase 0b: CONCURRENT in different waves: coef via constexpr descriptors
//            (thr 0..287) ∥ Bloch once (thr 512..1023: elem=t>>3, wire=t&7)
//  Phase 1:  wave k evaluates template chunk [18k,18k+18) (lane = elem)
//  Phase 2:  combine partials -> zvc[64][8] (thr 0..511)
//  Phase 3:  wave k projects+LNs elements [4k,4k+4)
// ===========================================================================
__global__ __launch_bounds__(1024) void qbranch_fused(
    const float* __restrict__ x,       // (B,8)
    const float* __restrict__ weights, // (2,8,3)
    const float* __restrict__ Wm,      // (8,64)
    const float* __restrict__ bias,    // (64)
    const float* __restrict__ gamma,   // (64)
    const float* __restrict__ beta,    // (64)
    float* __restrict__ out,           // (B,64)
    int B)
{
  __shared__ float u0s[8][4];
  __shared__ float gshf[25];          // [w*3+k]; [24] = 1.0 identity
  __shared__ float cf[NTERMS];
  __shared__ float blo[64*25];        // [elem][wire*3+c], pad 25 (6.4 KB)
  __shared__ float part[16][64][9];   // [chunk][lane][wi], pad 9 (36.9 KB)
  __shared__ float zvc[64][8];

  const int tid  = threadIdx.x;
  const int k    = tid >> 6;          // wave id 0..15
  const int lane = tid & 63;
  const int base = blockIdx.x * 64;

  // --- Phase 0a: trig ------------------------------------------------------
  if (tid < 8) {
    float phi = weights[tid*3 + 0], th = weights[tid*3 + 1], om = weights[tid*3 + 2];
    float ct = cosf(th*0.5f), st = sinf(th*0.5f);
    float ap = (phi + om)*0.5f, am = (phi - om)*0.5f;
    u0s[tid][0] =  cosf(ap)*ct;   // u00r
    u0s[tid][1] = -sinf(ap)*ct;   // u00i
    u0s[tid][2] = -cosf(am)*st;   // u01r
    u0s[tid][3] = -sinf(am)*st;   // u01i
    float phi1 = weights[(8+tid)*3 + 0], th1 = weights[(8+tid)*3 + 1];
    float s1 = sinf(th1), c1 = cosf(th1);
    gshf[tid*3 + 0] = -s1*cosf(phi1);
    gshf[tid*3 + 1] =  s1*sinf(phi1);
    gshf[tid*3 + 2] =  c1;
  }
  if (tid == 8) gshf[24] = 1.0f;
  __syncthreads();

  // --- Phase 0b: coef (waves 0-4) CONCURRENT with Bloch (waves 8-15) ------
  if (tid < NTERMS) {
    const unsigned int de = CFD_TAB.d[tid];
    float c = gshf[de & 0xFFu]
            * gshf[(de >> 8)  & 0xFFu]
            * gshf[(de >> 16) & 0xFFu]
            * gshf[(de >> 24) & 0x7Fu];
    cf[tid] = (de & 0x80000000u) ? -c : c;
  }
  if (tid >= 512) {
    const int t   = tid - 512;
    const int e   = t >> 3;           // element 0..63
    const int w   = t & 7;            // wire
    const int el  = (base + e < B) ? (base + e) : (B - 1);
    const float xv = x[(size_t)el*8 + w];
    const float th = 1.f - 2.f / (__expf(2.f*xv) + 1.f);   // tanh
    const float ha = th * (PI_F * 0.5f);
    const float c = __cosf(ha), s = __sinf(ha);
    const float u00r = u0s[w][0], u00i = u0s[w][1];
    const float u01r = u0s[w][2], u01i = u0s[w][3];
    const float x0r =  u00r*c + u01i*s;
    const float x0i =  u00i*c - u01r*s;
    const float x1r = -u01r*c - u00i*s;
    const float x1i =  u01i*c - u00r*s;
    float* row = blo + e*25 + w*3;
    row[0] = 2.f*(x0r*x1r + x0i*x1i);
    row[1] = 2.f*(x0r*x1i - x0i*x1r);
    row[2] = x0r*x0r + x0i*x0i - x1r*x1r - x1i*x1i;
  }
  __syncthreads();

  // --- Phase 1: load Bloch from LDS + this wave's 18-term chunk -----------
  B8 bx, by, bz;
  {
    const float* row = blo + lane*25;
    loadBloch<0>(row, bx, by, bz);
    loadBloch<1>(row, bx, by, bz);
    loadBloch<2>(row, bx, by, bz);
    loadBloch<3>(row, bx, by, bz);
    loadBloch<4>(row, bx, by, bz);
    loadBloch<5>(row, bx, by, bz);
    loadBloch<6>(row, bx, by, bz);
    loadBloch<7>(row, bx, by, bz);
  }

  B8 zv = {0.f,0.f,0.f,0.f,0.f,0.f,0.f,0.f};
  switch (k) {
    case  0: evalRange<  0,  18>(cf, bx, by, bz, zv); break;
    case  1: evalRange< 18,  36>(cf, bx, by, bz, zv); break;
    case  2: evalRange< 36,  54>(cf, bx, by, bz, zv); break;
    case  3: evalRange< 54,  72>(cf, bx, by, bz, zv); break;
    case  4: evalRange< 72,  90>(cf, bx, by, bz, zv); break;
    case  5: evalRange< 90, 108>(cf, bx, by, bz, zv); break;
    case  6: evalRange<108, 126>(cf, bx, by, bz, zv); break;
    case  7: evalRange<126, 144>(cf, bx, by, bz, zv); break;
    case  8: evalRange<144, 162>(cf, bx, by, bz, zv); break;
    case  9: evalRange<162, 180>(cf, bx, by, bz, zv); break;
    case 10: evalRange<180, 198>(cf, bx, by, bz, zv); break;
    case 11: evalRange<198, 216>(cf, bx, by, bz, zv); break;
    case 12: evalRange<216, 234>(cf, bx, by, bz, zv); break;
    case 13: evalRange<234, 252>(cf, bx, by, bz, zv); break;
    case 14: evalRange<252, 270>(cf, bx, by, bz, zv); break;
    case 15: evalRange<270, 288>(cf, bx, by, bz, zv); break;
  }
  storePart<0>(part, zv, k, lane);
  __syncthreads();

  // --- Phase 2: combine -> zvc[elem][wi] (threads 0..511) -----------------
  if (tid < 512) {
    const int lr = tid >> 3;
    const int wi = tid & 7;
    float s = 0.f;
#pragma unroll
    for (int kk = 0; kk < 16; ++kk) s += part[kk][lr][wi];
    zvc[lr][wi] = s;
  }
  __syncthreads();

  // --- Phase 3: projection + LN. Wave k handles elements [4k, 4k+4) -------
  const int j = lane;
  const float w0 = Wm[0*64+j], w1 = Wm[1*64+j], w2 = Wm[2*64+j], w3 = Wm[3*64+j];
  const float w4 = Wm[4*64+j], w5 = Wm[5*64+j], w6 = Wm[6*64+j], w7 = Wm[7*64+j];
  const float bj = bias[j], gj = gamma[j], btj = beta[j];
  const bool lb0 = (lane & 1) != 0;

#pragma unroll
  for (int e = 0; e < 4; ++e) {
    const int l = k*4 + e;
    if (base + l >= B) break;
    const float s0 = zvc[l][0], s1 = zvc[l][1], s2 = zvc[l][2], s3 = zvc[l][3];
    const float s4 = zvc[l][4], s5 = zvc[l][5], s6 = zvc[l][6], s7 = zvc[l][7];
    float h = bj;
    h = fmaf(s0, w0, h); h = fmaf(s1, w1, h); h = fmaf(s2, w2, h); h = fmaf(s3, w3, h);
    h = fmaf(s4, w4, h); h = fmaf(s5, w5, h); h = fmaf(s6, w6, h); h = fmaf(s7, w7, h);

    float S = h, Q = h*h;
    float snd = lb0 ? S : Q;
    float acc = (lb0 ? Q : S) + lxor<1>(snd, lane);
    acc += lxor< 2>(acc, lane);
    acc += lxor< 4>(acc, lane);
    acc += lxor< 8>(acc, lane);
    acc += lxor<16>(acc, lane);
    acc += lxor<32>(acc, lane);
    const float Ssum = breadl<0>(acc);
    const float Qsum = breadl<1>(acc);
    const float mu  = Ssum * (1.f/64.f);
    const float var = fmaf(-mu, mu, Qsum * (1.f/64.f));

    out[(size_t)(base + l)*64 + j] =
        fmaf((h - mu) * rsqrtf(var + 1e-5f), gj, btj);
  }
}

// ---------------------------------------------------------------------------
extern "C" void kernel_launch(void* const* d_in, const int* in_sizes, int n_in,
                              void* d_out, int out_size, void* d_ws, size_t ws_size,
                              hipStream_t stream)
{
  const float* x       = (const float*)d_in[0];
  const float* weights = (const float*)d_in[1];
  const float* Wm      = (const float*)d_in[2];
  const float* bias    = (const float*)d_in[3];
  const float* gamma   = (const float*)d_in[4];
  const float* beta    = (const float*)d_in[5];
  float* out = (float*)d_out;

  const int B = in_sizes[0] / 8;

  hipLaunchKernelGGL(qbranch_fused, dim3((B + 63) / 64), dim3(1024), 0, stream,
                     x, weights, Wm, bias, gamma, beta, out, B);
}